// Round 16
// baseline (86.498 us; speedup 1.0000x reference)
//
#include <hip/hip_runtime.h>

#define NN 100000
#define NE 3200000
#define NQ (NE / 4)            // 800000 int4 quads

// ---- bucketed-scatter plan constants ----
#define NCHUNK 32
#define CHUNK 3125             // dst chunk: 32*3125 = 100000; 12.5 KB LDS acc
#define NBB 512                // bucket blocks
#define BCAP 320               // per-(chunk,block) capacity: mean 195 + 9 sigma
#define NSLICE 8               // scatter slices (256 blocks, 1/CU)
#define GPS (NBB / NSLICE)     // segments per scatter slice = 64
#define QPSEG (BCAP / 4)       // 80 uint4 quads per segment
#define BLK_QUADS (GPS * BCAP / 4)   // 5120 quads per scatter block -> 5/thread

#define NBAND 8
#define BAND 12800             // src band: 51.2 KB LDS window (16B-aligned)
#define BAND_F4 (BAND / 4)     // 3200 float4 per full band
#define NF4_TOT (NN / 4)       // 25000 float4 in h

// --------------------------------------------------------------------------
// Bucket (R6/R12-exact, proven ~10-12 us): partition edges by dst-chunk.
// Packed: dst_local(12b)<<17 | src(17b).
__global__ __launch_bounds__(1024) void bucket_kernel(
        const int4* __restrict__ src4, const int4* __restrict__ dst4,
        unsigned* __restrict__ bkt, int* __restrict__ counts) {
    __shared__ int cnt[NCHUNK];
    if (threadIdx.x < NCHUNK) cnt[threadIdx.x] = 0;
    __syncthreads();
    const int b = blockIdx.x;
    const int q0 = (int)(((long long)b * NQ) / NBB);
    const int q1 = (int)(((long long)(b + 1) * NQ) / NBB);
    for (int q = q0 + threadIdx.x; q < q1; q += 1024) {
        const int4 d = dst4[q];
        const int4 s = src4[q];
        const int dd[4] = {d.x, d.y, d.z, d.w};
        const int ss[4] = {s.x, s.y, s.z, s.w};
#pragma unroll
        for (int j = 0; j < 4; ++j) {
            const int c = dd[j] / CHUNK;                  // magic-mul div
            const int slot = atomicAdd(&cnt[c], 1);
            bkt[((size_t)c * NBB + b) * BCAP + slot] =
                ((unsigned)(dd[j] - c * CHUNK) << 17) | (unsigned)ss[j];
        }
    }
    __syncthreads();
    if (threadIdx.x < NCHUNK)
        counts[threadIdx.x * NBB + b] = cnt[threadIdx.x];
}

// --------------------------------------------------------------------------
// Banded-LDS scatter: block (s,c) holds its 20 entries/thread in registers;
// iterates 8 src-bands, staging each 51.2 KB h-window into LDS (coalesced
// float4 from L2), then resolves in-band entries via LDS gather + LDS atomic.
// Converts 3.2M random global gathers into coalesced streams + LDS reads.
__global__ __launch_bounds__(1024) void scatter_band_kernel(
        const float* __restrict__ h,
        const unsigned* __restrict__ bkt, const int* __restrict__ counts,
        float* __restrict__ partial) {
    __shared__ float hwin[BAND];     // 51.2 KB
    __shared__ float acc[CHUNK];     // 12.5 KB
    __shared__ int cnt_l[GPS];
    const int s = blockIdx.x, c = blockIdx.y;
    const int tid = threadIdx.x;
    for (int i = tid; i < CHUNK; i += 1024) acc[i] = 0.0f;
    if (tid < GPS) cnt_l[tid] = counts[c * NBB + s * GPS + tid];
    __syncthreads();

    // preload this thread's 5 quads (20 entries) + validity counts
    const uint4* mp4 = (const uint4*)(bkt + ((size_t)c * NBB + s * GPS) * BCAP);
    uint4 e[5];
    int nn[5], ii[5];
#pragma unroll
    for (int k = 0; k < 5; ++k) {
        const int quad = k * 1024 + tid;
        e[k] = mp4[quad];
        const int blk = quad / QPSEG;                     // magic-mul div
        ii[k] = (quad - blk * QPSEG) * 4;
        nn[k] = cnt_l[blk];
    }

    const float4* h4 = (const float4*)h;
    float4* hwin4 = (float4*)hwin;
    for (int band = 0; band < NBAND; ++band) {
        const int f4base = band * BAND_F4;
        const int nf4 = min(BAND_F4, NF4_TOT - f4base);
        for (int i = tid; i < nf4; i += 1024) hwin4[i] = h4[f4base + i];
        __syncthreads();
        const unsigned blo = (unsigned)(band * BAND);
#pragma unroll
        for (int k = 0; k < 5; ++k) {
            const unsigned cx[4] = {e[k].x, e[k].y, e[k].z, e[k].w};
#pragma unroll
            for (int j = 0; j < 4; ++j) {
                const unsigned loc = (cx[j] & 0x1FFFFu) - blo;
                if (ii[k] + j < nn[k] && loc < (unsigned)BAND)
                    atomicAdd(&acc[cx[j] >> 17], hwin[loc]);
            }
        }
        __syncthreads();
    }
    float* outp = partial + ((size_t)c * NSLICE + s) * CHUNK;
    for (int i = tid; i < CHUNK; i += 1024) outp[i] = acc[i];
}

// agg = sum over 8 slice partials; epilogue MLP / bias+relu.
__global__ __launch_bounds__(256) void reduce_mlp_kernel(
        const float* __restrict__ partial,
        const float* __restrict__ W1, const float* __restrict__ b1,
        const float* __restrict__ W2,
        float* __restrict__ sout, int n) {
    int i = blockIdx.x * blockDim.x + threadIdx.x;
    if (i >= n) return;
    const int c = i / CHUNK;
    const int idx = i - c * CHUNK;
    const float* base = partial + (size_t)c * NSLICE * CHUNK + idx;
    float a = 0.0f;
#pragma unroll
    for (int s = 0; s < NSLICE; ++s) a += base[(size_t)s * CHUNK];
    float r = 0.0f;
#pragma unroll
    for (int j = 0; j < 16; ++j)
        r = fmaf(fmaxf(fmaf(a, W1[j], b1[j]), 0.0f), W2[j], r);
    sout[i] = r;
}

__global__ __launch_bounds__(256) void reduce_final_kernel(
        const float* __restrict__ partial,
        const float* __restrict__ b2,
        float* __restrict__ out, int n) {
    int i = blockIdx.x * blockDim.x + threadIdx.x;
    if (i >= n) return;
    const int c = i / CHUNK;
    const int idx = i - c * CHUNK;
    const float* base = partial + (size_t)c * NSLICE * CHUNK + idx;
    float a = 0.0f;
#pragma unroll
    for (int s = 0; s < NSLICE; ++s) a += base[(size_t)s * CHUNK];
    out[i] = fmaxf(a + b2[0], 0.0f);
}

// ---------------- Fallback: global-atomic path ------------------------------
__global__ void zero_kernel(float* __restrict__ p, int n) {
    int i = blockIdx.x * blockDim.x + threadIdx.x;
    int st = gridDim.x * blockDim.x;
    for (; i < n; i += st) p[i] = 0.0f;
}
__global__ __launch_bounds__(256) void edge_scatter_kernel(
        const float* __restrict__ h, const int4* __restrict__ src4,
        const int4* __restrict__ dst4, float* __restrict__ agg, int nquad) {
    int i = blockIdx.x * blockDim.x + threadIdx.x;
    if (i >= nquad) return;
    int4 s = src4[i]; int4 d = dst4[i];
    atomicAdd(&agg[d.x], h[s.x]);
    atomicAdd(&agg[d.y], h[s.y]);
    atomicAdd(&agg[d.z], h[s.z]);
    atomicAdd(&agg[d.w], h[s.w]);
}
__global__ __launch_bounds__(256) void mlp_kernel(
        const float* __restrict__ agg1, const float* __restrict__ W1,
        const float* __restrict__ b1, const float* __restrict__ W2,
        float* __restrict__ sout, int n) {
    int i = blockIdx.x * blockDim.x + threadIdx.x;
    if (i >= n) return;
    float a = agg1[i], r = 0.0f;
#pragma unroll
    for (int j = 0; j < 16; ++j)
        r = fmaf(fmaxf(fmaf(a, W1[j], b1[j]), 0.0f), W2[j], r);
    sout[i] = r;
}
__global__ __launch_bounds__(256) void finalize_kernel(
        float* __restrict__ out, const float* __restrict__ b2, int n) {
    int i = blockIdx.x * blockDim.x + threadIdx.x;
    if (i >= n) return;
    out[i] = fmaxf(out[i] + b2[0], 0.0f);
}

extern "C" void kernel_launch(void* const* d_in, const int* in_sizes, int n_in,
                              void* d_out, int out_size, void* d_ws, size_t ws_size,
                              hipStream_t stream) {
    const float* features = (const float*)d_in[0];
    const int*   src      = (const int*)d_in[1];
    const int*   dst      = (const int*)d_in[2];
    const float* W1       = (const float*)d_in[3];
    const float* b1       = (const float*)d_in[4];
    const float* W2       = (const float*)d_in[5];
    const float* b2       = (const float*)d_in[6];
    float* out = (float*)d_out;

    const int4* src4 = (const int4*)src;
    const int4* dst4 = (const int4*)dst;
    const int nb = (NN + 255) / 256;

    // Plan A: bucket + banded-LDS scatter (~25 MB ws)
    {
        const size_t bkt_elems  = (size_t)NCHUNK * NBB * BCAP;       // 5.24M u32
        const size_t cnt_elems  = (size_t)NCHUNK * NBB;              // 16384 int
        const size_t part_elems = (size_t)NCHUNK * NSLICE * CHUNK;   // 800K f32
        const size_t need = (bkt_elems + cnt_elems + part_elems + NN) * 4;
        if (ws_size >= need) {
            unsigned* bkt  = (unsigned*)d_ws;
            int* counts    = (int*)(bkt + bkt_elems);
            float* partial = (float*)(counts + cnt_elems);
            float* sbuf    = partial + part_elems;

            bucket_kernel<<<NBB, 1024, 0, stream>>>(src4, dst4, bkt, counts);
            dim3 g(NSLICE, NCHUNK);
            scatter_band_kernel<<<g, 1024, 0, stream>>>(features, bkt, counts, partial);
            reduce_mlp_kernel<<<nb, 256, 0, stream>>>(partial, W1, b1, W2, sbuf, NN);
            scatter_band_kernel<<<g, 1024, 0, stream>>>(sbuf, bkt, counts, partial);
            reduce_final_kernel<<<nb, 256, 0, stream>>>(partial, b2, out, NN);
            return;
        }
    }
    // Fallback: global atomics
    {
        float* agg1 = (float*)d_ws;
        float* sbuf = agg1 + NN;
        const int eb = (NQ + 255) / 256;
        zero_kernel<<<256, 256, 0, stream>>>(agg1, NN);
        edge_scatter_kernel<<<eb, 256, 0, stream>>>(features, src4, dst4, agg1, NQ);
        mlp_kernel<<<nb, 256, 0, stream>>>(agg1, W1, b1, W2, sbuf, NN);
        zero_kernel<<<256, 256, 0, stream>>>(out, NN);
        edge_scatter_kernel<<<eb, 256, 0, stream>>>(sbuf, src4, dst4, out, NQ);
        finalize_kernel<<<nb, 256, 0, stream>>>(out, b2, NN);
    }
}